// Round 9
// baseline (137.102 us; speedup 1.0000x reference)
//
#include <hip/hip_runtime.h>

#define W_ 352
#define H_ 128
#define HW 45056
#define D_ 48
#define B_ 2
#define N_ 6
#define DHW (D_*HW)          // 2,162,688
#define PC_SIZE (36*DHW)     // 77,856,768
#define BHW (B_*HW)          // 90,112
#define BEVN (B_*64*HW)      // 5,767,168

#define WS_KINV 0     // 12*9 = 108 floats
#define WS_SUM1 192
#define WS_SQ1  256
#define WS_SUM2 448
#define WS_SQ2  512

#define NBN_BLK (BEVN/2048)      // 2816
#define NPC_BLK 4224             // grid-stride pc blocks
#define PC_ITER 18               // 4224*18*1024 = PC_SIZE

typedef unsigned short ushort_t;
typedef __attribute__((ext_vector_type(8))) short bf16x8;
typedef __attribute__((ext_vector_type(4))) float f32x4;
typedef __attribute__((ext_vector_type(8))) unsigned short u16x8;

static __device__ inline ushort_t f2bf(float f) {
    union { float f; unsigned u; } v; v.f = f;
    unsigned r = v.u + 0x7FFF + ((v.u >> 16) & 1);
    return (ushort_t)(r >> 16);
}
static __device__ inline float bf2f(ushort_t u) {
    union { unsigned u; float f; } v; v.u = ((unsigned)u) << 16; return v.f;
}
static __device__ inline void invert3x3(const float* __restrict__ M, float* __restrict__ o) {
    float a = M[0], b = M[1], c = M[2];
    float d = M[4], e = M[5], f = M[6];
    float g = M[8], h = M[9], ii = M[10];
    float det = a*(e*ii - f*h) - b*(d*ii - f*g) + c*(d*h - e*g);
    float inv = 1.f / det;
    o[0] = (e*ii - f*h)*inv; o[1] = (c*h - b*ii)*inv; o[2] = (b*f - c*e)*inv;
    o[3] = (f*g - d*ii)*inv; o[4] = (a*ii - c*g)*inv; o[5] = (c*d - a*f)*inv;
    o[6] = (d*h - e*g)*inv;  o[7] = (b*g - a*h)*inv;  o[8] = (a*e - b*d)*inv;
}

// ---- K1: fused bevf -> conv1 -> BN1 partial stats, + w2 prepack ----------
// blocks [0,352): 32x8 output tile per block (b = bid/176).
// blocks [352,496): prepack w2 into swizzled bf16.
__global__ __launch_bounds__(256) void k_fused1(const float* __restrict__ K4,
                                                const float* __restrict__ datt,
                                                const float* __restrict__ vatt,
                                                const float* __restrict__ depths,
                                                const float* __restrict__ w1,
                                                const float* __restrict__ b1,
                                                const float* __restrict__ w2,
                                                float* __restrict__ ws,
                                                ushort_t* __restrict__ h1pm,
                                                ushort_t* __restrict__ packedW) {
    int bid = blockIdx.x, tid = threadIdx.x;
    if (bid >= 352) {   // weight prepack for conv2
        int e = (bid - 352) * 256 + tid;   // [0, 36864)
        int tap = e >> 12;
        int r   = e & 4095;
        int n   = r >> 6, k = r & 63;
        int slot = (k >> 3) ^ (n & 7);
        packedW[tap * 4096 + n * 64 + slot * 8 + (k & 7)] = f2bf(w2[(n * 64 + k) * 9 + tap]);
        return;
    }
    if (bid == 0 && tid >= 128 && tid < 140)   // publish Kinv rows for K3
        invert3x3(K4 + (tid - 128) * 16, ws + WS_KINV + (tid - 128) * 9);

    __shared__ float sBev[3][10][34];
    __shared__ float wl[64 * 27];
    __shared__ float sDep[48], sDa[48], sKinv[54];
    __shared__ __align__(16) ushort_t sTile[256 * 64];   // conv1 out, pixel-major
    __shared__ float sSum[64], sSq[64];

    int b  = bid / 176;
    int t0 = bid - b * 176;
    int ty = t0 / 11, tx = t0 - ty * 11;
    int y0 = ty * 8, x0 = tx * 32;

    if (tid < 48) sDep[tid] = depths[tid];
    if (tid < 64) { sSum[tid] = 0.f; sSq[tid] = 0.f; }
    if (tid >= 64 && tid < 70) invert3x3(K4 + (b * 6 + tid - 64) * 16, sKinv + (tid - 64) * 9);
    if (tid == 192) {
        float mx = -1e30f;
        for (int k = 0; k < D_; k++) mx = fmaxf(mx, datt[k]);
        float s = 0.f, e[D_];
        for (int k = 0; k < D_; k++) { e[k] = expf(datt[k] - mx); s += e[k]; }
        float invs = 1.f / s;
        for (int k = 0; k < D_; k++) sDa[k] = e[k] * invs;
    }
    for (int i = tid; i < 64 * 27; i += 256) wl[i] = w1[i];
    __syncthreads();

    // phase A: bevf on the 34x10 halo (this batch's 3 channels)
    for (int idx = tid; idx < 340; idx += 256) {
        int hy = idx / 34, hx = idx - hy * 34;
        int py = y0 + hy - 1, px = x0 + hx - 1;
        float a0 = 0.f, a1 = 0.f, a2 = 0.f;
        if ((unsigned)py < H_ && (unsigned)px < W_) {
            int pix = py * W_ + px;
            float va[N_]; float mx = -1e30f;
            for (int n = 0; n < N_; n++) { va[n] = vatt[n * HW + pix]; mx = fmaxf(mx, va[n]); }
            float s = 0.f;
            for (int n = 0; n < N_; n++) { va[n] = expf(va[n] - mx); s += va[n]; }
            float invs = 1.f / s;
            int q0 = pix * 48;
            int d = q0 / HW;
            int p = q0 - d * HW;
            int y = p / W_;
            int x = p - y * W_;
            float fx = (float)x, fy = (float)y;
            float S0 = 0.f, S1 = 0.f, S2 = 0.f;
            #pragma unroll
            for (int dd = 0; dd < D_; dd++) {
                float wq = sDa[dd] * sDep[d];
                S0 = fmaf(wq, fx, S0);
                S1 = fmaf(wq, fy, S1);
                S2 += wq;
                x++; fx += 1.f;
                if (x == W_) { x = 0; fx = 0.f; y++; fy += 1.f; if (y == H_) { y = 0; fy = 0.f; d++; } }
            }
            for (int n = 0; n < N_; n++) {
                float van = va[n] * invs;
                const float* kv = sKinv + n * 9;
                a0 = fmaf(van, fmaf(kv[0], S0, fmaf(kv[1], S1, kv[2] * S2)), a0);
                a1 = fmaf(van, fmaf(kv[3], S0, fmaf(kv[4], S1, kv[5] * S2)), a1);
                a2 = fmaf(van, fmaf(kv[6], S0, fmaf(kv[7], S1, kv[8] * S2)), a2);
            }
        }
        sBev[0][hy][hx] = a0;
        sBev[1][hy][hx] = a1;
        sBev[2][hy][hx] = a2;
    }
    __syncthreads();

    // phase B: conv1 3->64 from LDS, pixel-major bf16 out (global + LDS tile)
    int oy = tid >> 5, ox = tid & 31;
    int y = y0 + oy, x = x0 + ox;
    float v[27];
    #pragma unroll
    for (int ci = 0; ci < 3; ci++)
        #pragma unroll
        for (int dy = 0; dy < 3; dy++)
            #pragma unroll
            for (int dx = 0; dx < 3; dx++)
                v[ci * 9 + dy * 3 + dx] = sBev[ci][oy + dy][ox + dx];
    u16x8 pack[8];
    #pragma unroll
    for (int co = 0; co < 64; co++) {
        float acc = b1[co];
        #pragma unroll
        for (int k = 0; k < 27; k++) acc = fmaf(wl[co * 27 + k], v[k], acc);
        pack[co >> 3][co & 7] = (short)f2bf(acc);
    }
    ushort_t* dst = h1pm + (size_t)(b * HW + y * W_ + x) * 64;
    #pragma unroll
    for (int j = 0; j < 8; j++) {
        *(u16x8*)(dst + j * 8) = pack[j];
        *(u16x8*)(&sTile[tid * 64 + j * 8]) = pack[j];
    }
    __syncthreads();

    // phase C: BN1 partial stats from LDS tile (k_stats scheme, LDS-sourced)
    int c8 = tid & 7;
    int lp = tid >> 3;           // 0..31
    float s[8] = {0,0,0,0,0,0,0,0}, q[8] = {0,0,0,0,0,0,0,0};
    for (int p = lp; p < 256; p += 32) {
        u16x8 vv = *(const u16x8*)(&sTile[p * 64 + c8 * 8]);
        #pragma unroll
        for (int e = 0; e < 8; e++) {
            float f = bf2f(vv[e]);
            s[e] += f;
            q[e] = fmaf(f, f, q[e]);
        }
    }
    #pragma unroll
    for (int e = 0; e < 8; e++) {
        s[e] += __shfl_xor(s[e], 8);  s[e] += __shfl_xor(s[e], 16); s[e] += __shfl_xor(s[e], 32);
        q[e] += __shfl_xor(q[e], 8);  q[e] += __shfl_xor(q[e], 16); q[e] += __shfl_xor(q[e], 32);
    }
    if ((tid & 56) == 0) {
        #pragma unroll
        for (int e = 0; e < 8; e++) {
            atomicAdd(&sSum[c8 * 8 + e], s[e]);
            atomicAdd(&sSq[c8 * 8 + e], q[e]);
        }
    }
    __syncthreads();
    if (tid < 64) {
        atomicAdd(ws + WS_SUM1 + tid, sSum[tid]);
        atomicAdd(ws + WS_SQ1 + tid, sSq[tid]);
    }
}

// ---- K2: conv2 MFMA implicit GEMM; BN1 fused in, fp32 out to bev region,
//          BN2 partial stats fused out ------------------------------------
__global__ __launch_bounds__(256) void k_conv2(const ushort_t* __restrict__ h1pm,
                                               const ushort_t* __restrict__ packedW,
                                               const float* __restrict__ b2,
                                               const float* __restrict__ g1,
                                               const float* __restrict__ bb1,
                                               float* __restrict__ ws,
                                               float* __restrict__ h2f) {
    __shared__ __align__(16) ushort_t sA[204 * 64];
    __shared__ __align__(16) ushort_t sB[3 * 4096];
    __shared__ float sSc[64], sSh[64];
    __shared__ float sRs[4][64], sRq[4][64];

    const int tid = threadIdx.x;
    if (tid < 64) {   // BN1 finalize
        const float invM = 1.f / (float)BHW;
        float m = ws[WS_SUM1 + tid] * invM;
        float var = ws[WS_SQ1 + tid] * invM - m * m;
        float sc = g1[tid] * rsqrtf(var + 1e-5f);
        sSc[tid] = sc;
        sSh[tid] = bb1[tid] - m * sc;
    }
    __syncthreads();

    const int bid = blockIdx.x;
    const int b  = bid / 352;
    const int r0 = bid - b * 352;
    const int yb = r0 / 11;
    const int xb = r0 - yb * 11;
    const int x0 = xb * 32;
    const int y0 = yb * 4;
    const ushort_t* h1p = h1pm + (size_t)b * HW * 64;

    // stage A: 204 halo pixels x 64ch, BN1+ReLU, swizzled
    for (int idx = tid; idx < 204 * 8; idx += 256) {
        int r  = idx >> 3;
        int c8 = idx & 7;
        int hy = r / 34;
        int hx = r - hy * 34;
        int py = y0 + hy - 1, px = x0 + hx - 1;
        u16x8 ov = {0, 0, 0, 0, 0, 0, 0, 0};
        if ((unsigned)py < H_ && (unsigned)px < W_) {
            u16x8 v = *(const u16x8*)(h1p + (size_t)(py * W_ + px) * 64 + c8 * 8);
            #pragma unroll
            for (int e = 0; e < 8; e++) {
                int ci = c8 * 8 + e;
                float f = fmaxf(fmaf(sSc[ci], bf2f(v[e]), sSh[ci]), 0.f);
                ov[e] = (short)f2bf(f);
            }
        }
        int slot = c8 ^ (r & 7);
        *(u16x8*)(&sA[r * 64 + slot * 8]) = ov;
    }

    const int w    = tid >> 6;
    const int lane = tid & 63;
    const int g    = lane >> 4;
    const int c16  = lane & 15;

    f32x4 acc[2][4];
    #pragma unroll
    for (int m = 0; m < 2; m++)
        #pragma unroll
        for (int n = 0; n < 4; n++)
            acc[m][n] = (f32x4){0.f, 0.f, 0.f, 0.f};

    for (int grp = 0; grp < 3; grp++) {      // grp == dy
        __syncthreads();
        const uint4* src = (const uint4*)(packedW + grp * 3 * 4096);
        uint4* dst = (uint4*)sB;
        #pragma unroll
        for (int i = 0; i < 6; i++) dst[tid + 256 * i] = src[tid + 256 * i];
        __syncthreads();
        #pragma unroll
        for (int tt = 0; tt < 3; tt++) {     // tt == dx
            bf16x8 afr[2][2];
            #pragma unroll
            for (int mrep = 0; mrep < 2; mrep++)
                #pragma unroll
                for (int kk = 0; kk < 2; kk++) {
                    int r = (w + grp) * 34 + tt + c16 + 16 * mrep;
                    int slot = (g + 4 * kk) ^ (r & 7);
                    afr[mrep][kk] = *(const bf16x8*)(&sA[r * 64 + slot * 8]);
                }
            #pragma unroll
            for (int nrep = 0; nrep < 4; nrep++) {
                int n = 16 * nrep + c16;
                #pragma unroll
                for (int kk = 0; kk < 2; kk++) {
                    int slot = (g + 4 * kk) ^ (n & 7);
                    bf16x8 bfr = *(const bf16x8*)(&sB[tt * 4096 + n * 64 + slot * 8]);
                    #pragma unroll
                    for (int mrep = 0; mrep < 2; mrep++)
                        acc[mrep][nrep] = __builtin_amdgcn_mfma_f32_16x16x32_bf16(
                            afr[mrep][kk], bfr, acc[mrep][nrep], 0, 0, 0);
                }
            }
        }
    }

    // epilogue: bias, fp32 store to bev region (channel-major), BN2 stats
    const int y = y0 + w;
    #pragma unroll
    for (int nrep = 0; nrep < 4; nrep++) {
        int co = 16 * nrep + c16;
        float bias = b2[co];
        float* dstrow = h2f + (size_t)(b * 64 + co) * HW + y * W_;
        float s = 0.f, q = 0.f;
        #pragma unroll
        for (int mrep = 0; mrep < 2; mrep++)
            #pragma unroll
            for (int j = 0; j < 4; j++) {
                float val = acc[mrep][nrep][j] + bias;
                s += val;
                q = fmaf(val, val, q);
                dstrow[x0 + 16 * mrep + g * 4 + j] = val;
            }
        s += __shfl_xor(s, 16); s += __shfl_xor(s, 32);
        q += __shfl_xor(q, 16); q += __shfl_xor(q, 32);
        if (g == 0) { sRs[w][co] = s; sRq[w][co] = q; }
    }
    __syncthreads();
    if (tid < 64) {
        float s = sRs[0][tid] + sRs[1][tid] + sRs[2][tid] + sRs[3][tid];
        float q = sRq[0][tid] + sRq[1][tid] + sRq[2][tid] + sRq[3][tid];
        atomicAdd(ws + WS_SUM2 + tid, s);
        atomicAdd(ws + WS_SQ2 + tid, q);
    }
}

// ---- K3: tail = BN2+ReLU in-place on bev + grid-stride pc writes ---------
__global__ __launch_bounds__(256) void k_tail(const float* __restrict__ depths,
                                              const float* __restrict__ ws,
                                              const float* __restrict__ g2,
                                              const float* __restrict__ bb2,
                                              float* __restrict__ out) {
    int bid = blockIdx.x, tid = threadIdx.x;
    if (bid >= NBN_BLK) {
        int pcbid = bid - NBN_BLK;   // [0, NPC_BLK)
        for (int i = 0; i < PC_ITER; i++) {
            int ch = i * NPC_BLK + pcbid;
            int f = ch * 1024 + tid * 4;
            int bnc = f / DHW;
            int r1  = f - bnc * DHW;
            int d   = r1 / HW;
            int p   = r1 - d * HW;
            int y   = p / W_;
            int x   = p - y * W_;
            float ka = ws[WS_KINV + bnc * 3 + 0];
            float kb = ws[WS_KINV + bnc * 3 + 1];
            float kc = ws[WS_KINV + bnc * 3 + 2];
            float dep = depths[d];
            float base = fmaf(kb, (float)y, kc);
            f32x4 v;
            v.x = dep * fmaf(ka, (float)(x + 0), base);
            v.y = dep * fmaf(ka, (float)(x + 1), base);
            v.z = dep * fmaf(ka, (float)(x + 2), base);
            v.w = dep * fmaf(ka, (float)(x + 3), base);
            *(f32x4*)(out + f) = v;
        }
        return;
    }
    float* bev = out + PC_SIZE;
    int t = bid * 256 + tid;
    int f = t * 8;
    int c = (f / HW) & 63;
    const float invM = 1.f / (float)BHW;
    float m = ws[WS_SUM2 + c] * invM;
    float var = ws[WS_SQ2 + c] * invM - m * m;
    float sc = g2[c] * rsqrtf(var + 1e-5f);
    float sh = bb2[c] - m * sc;
    f32x4 a = *(f32x4*)(bev + f);
    f32x4 d = *(f32x4*)(bev + f + 4);
    a.x = fmaxf(fmaf(sc, a.x, sh), 0.f);
    a.y = fmaxf(fmaf(sc, a.y, sh), 0.f);
    a.z = fmaxf(fmaf(sc, a.z, sh), 0.f);
    a.w = fmaxf(fmaf(sc, a.w, sh), 0.f);
    d.x = fmaxf(fmaf(sc, d.x, sh), 0.f);
    d.y = fmaxf(fmaf(sc, d.y, sh), 0.f);
    d.z = fmaxf(fmaf(sc, d.z, sh), 0.f);
    d.w = fmaxf(fmaf(sc, d.w, sh), 0.f);
    *(f32x4*)(bev + f) = a;
    *(f32x4*)(bev + f + 4) = d;
}

extern "C" void kernel_launch(void* const* d_in, const int* in_sizes, int n_in,
                              void* d_out, int out_size, void* d_ws, size_t ws_size,
                              hipStream_t stream) {
    const float* K4     = (const float*)d_in[1];
    const float* vatt   = (const float*)d_in[3];
    const float* datt   = (const float*)d_in[4];
    const float* c1w    = (const float*)d_in[5];
    const float* c1b    = (const float*)d_in[6];
    const float* g1     = (const float*)d_in[7];
    const float* bb1    = (const float*)d_in[8];
    const float* c2w    = (const float*)d_in[9];
    const float* c2b    = (const float*)d_in[10];
    const float* g2     = (const float*)d_in[11];
    const float* bb2    = (const float*)d_in[12];
    const float* depths = (const float*)d_in[13];

    float* out = (float*)d_out;
    float* ws  = (float*)d_ws;
    char* base = (char*)d_out;
    // scratch at the start of the pc region (overwritten only by K3's pc part)
    ushort_t* h1pm    = (ushort_t*)base;                   // 11.53 MB [pix][64]
    ushort_t* packedW = (ushort_t*)(base + (12u << 20));   // 72 KB
    float*    h2f     = out + PC_SIZE;                     // bev region (fp32)

    hipMemsetAsync(ws, 0, 640 * sizeof(float), stream);
    k_fused1<<<496, 256, 0, stream>>>(K4, datt, vatt, depths, c1w, c1b, c2w, ws, h1pm, packedW);
    k_conv2 <<<704, 256, 0, stream>>>(h1pm, packedW, c2b, g1, bb1, ws, h2f);
    k_tail  <<<NBN_BLK + NPC_BLK, 256, 0, stream>>>(depths, ws, g2, bb2, out);
}

// Round 10
// 123.161 us; speedup vs baseline: 1.1132x; 1.1132x over previous
//
#include <hip/hip_runtime.h>

#define W_ 352
#define H_ 128
#define HW 45056
#define D_ 48
#define B_ 2
#define N_ 6
#define DHW (D_*HW)          // 2,162,688
#define PC_SIZE (36*DHW)     // 77,856,768
#define BHW (B_*HW)          // 90,112
#define BEVN (B_*64*HW)      // 5,767,168

#define WS_KINV 0     // 12*9 = 108 floats
#define WS_SUM1 192
#define WS_SQ1  256
#define WS_SUM2 448
#define WS_SQ2  512

#define NPC_BLK (PC_SIZE/1024)   // 76032 chunks of 4KB
#define CH_H2B0 4096             // h2b scratch = chunks [4096, 6912)
#define CH_H2B1 (CH_H2B0 + BEVN/2048)   // 6912

typedef unsigned short ushort_t;
typedef __attribute__((ext_vector_type(8))) short bf16x8;
typedef __attribute__((ext_vector_type(4))) float f32x4;
typedef __attribute__((ext_vector_type(8))) unsigned short u16x8;
typedef __attribute__((ext_vector_type(4))) unsigned short u16x4;

static __device__ inline ushort_t f2bf(float f) {
    union { float f; unsigned u; } v; v.f = f;
    unsigned r = v.u + 0x7FFF + ((v.u >> 16) & 1);
    return (ushort_t)(r >> 16);
}
static __device__ inline float bf2f(ushort_t u) {
    union { unsigned u; float f; } v; v.u = ((unsigned)u) << 16; return v.f;
}
static __device__ inline void invert3x3(const float* __restrict__ M, float* __restrict__ o) {
    float a = M[0], b = M[1], c = M[2];
    float d = M[4], e = M[5], f = M[6];
    float g = M[8], h = M[9], ii = M[10];
    float det = a*(e*ii - f*h) - b*(d*ii - f*g) + c*(d*h - e*g);
    float inv = 1.f / det;
    o[0] = (e*ii - f*h)*inv; o[1] = (c*h - b*ii)*inv; o[2] = (b*f - c*e)*inv;
    o[3] = (f*g - d*ii)*inv; o[4] = (a*ii - c*g)*inv; o[5] = (c*d - a*f)*inv;
    o[6] = (d*h - e*g)*inv;  o[7] = (b*g - a*h)*inv;  o[8] = (a*e - b*d)*inv;
}

// pc chunk writer: 1024 consecutive floats, 4/thread, contiguous per-lane
// f32x4 (wave = one 1KB segment), nontemporal. Kinv rows from ws.
static __device__ inline void pc_write(int pcblk, const float* __restrict__ ws,
                                       const float* __restrict__ depths,
                                       float* __restrict__ out) {
    int f = pcblk * 1024 + (int)threadIdx.x * 4;
    int bnc = f / DHW;
    int r1  = f - bnc * DHW;
    int d   = r1 / HW;
    int p   = r1 - d * HW;
    int y   = p / W_;
    int x   = p - y * W_;
    float ka = ws[WS_KINV + bnc * 3 + 0];
    float kb = ws[WS_KINV + bnc * 3 + 1];
    float kc = ws[WS_KINV + bnc * 3 + 2];
    float dep = depths[d];
    float base = fmaf(kb, (float)y, kc);
    f32x4 v;
    v.x = dep * fmaf(ka, (float)(x + 0), base);
    v.y = dep * fmaf(ka, (float)(x + 1), base);
    v.z = dep * fmaf(ka, (float)(x + 2), base);
    v.w = dep * fmaf(ka, (float)(x + 3), base);
    __builtin_nontemporal_store(v, (f32x4*)(out + f));
}

// ---- K1: fused bevf -> conv1 -> BN1 partial stats, + w2 prepack ----------
__global__ __launch_bounds__(256) void k_fused1(const float* __restrict__ K4,
                                                const float* __restrict__ datt,
                                                const float* __restrict__ vatt,
                                                const float* __restrict__ depths,
                                                const float* __restrict__ w1,
                                                const float* __restrict__ b1,
                                                const float* __restrict__ w2,
                                                float* __restrict__ ws,
                                                ushort_t* __restrict__ h1pm,
                                                ushort_t* __restrict__ packedW) {
    int bid = blockIdx.x, tid = threadIdx.x;
    if (bid >= 352) {   // weight prepack for conv2
        int e = (bid - 352) * 256 + tid;   // [0, 36864)
        int tap = e >> 12;
        int r   = e & 4095;
        int n   = r >> 6, k = r & 63;
        int slot = (k >> 3) ^ (n & 7);
        packedW[tap * 4096 + n * 64 + slot * 8 + (k & 7)] = f2bf(w2[(n * 64 + k) * 9 + tap]);
        return;
    }
    if (bid == 0 && tid >= 128 && tid < 140)   // publish Kinv rows for tail
        invert3x3(K4 + (tid - 128) * 16, ws + WS_KINV + (tid - 128) * 9);

    __shared__ float sBev[3][10][34];
    __shared__ float wl[64 * 27];
    __shared__ float sDep[48], sDa[48], sKinv[54];
    __shared__ __align__(16) ushort_t sTile[256 * 64];
    __shared__ float sSum[64], sSq[64];

    int b  = bid / 176;
    int t0 = bid - b * 176;
    int ty = t0 / 11, tx = t0 - ty * 11;
    int y0 = ty * 8, x0 = tx * 32;

    if (tid < 48) sDep[tid] = depths[tid];
    if (tid < 64) { sSum[tid] = 0.f; sSq[tid] = 0.f; }
    if (tid >= 64 && tid < 70) invert3x3(K4 + (b * 6 + tid - 64) * 16, sKinv + (tid - 64) * 9);
    if (tid == 192) {
        float mx = -1e30f;
        for (int k = 0; k < D_; k++) mx = fmaxf(mx, datt[k]);
        float s = 0.f, e[D_];
        for (int k = 0; k < D_; k++) { e[k] = expf(datt[k] - mx); s += e[k]; }
        float invs = 1.f / s;
        for (int k = 0; k < D_; k++) sDa[k] = e[k] * invs;
    }
    for (int i = tid; i < 64 * 27; i += 256) wl[i] = w1[i];
    __syncthreads();

    // phase A: bevf on the 34x10 halo
    for (int idx = tid; idx < 340; idx += 256) {
        int hy = idx / 34, hx = idx - hy * 34;
        int py = y0 + hy - 1, px = x0 + hx - 1;
        float a0 = 0.f, a1 = 0.f, a2 = 0.f;
        if ((unsigned)py < H_ && (unsigned)px < W_) {
            int pix = py * W_ + px;
            float va[N_]; float mx = -1e30f;
            for (int n = 0; n < N_; n++) { va[n] = vatt[n * HW + pix]; mx = fmaxf(mx, va[n]); }
            float s = 0.f;
            for (int n = 0; n < N_; n++) { va[n] = expf(va[n] - mx); s += va[n]; }
            float invs = 1.f / s;
            int q0 = pix * 48;
            int d = q0 / HW;
            int p = q0 - d * HW;
            int y = p / W_;
            int x = p - y * W_;
            float fx = (float)x, fy = (float)y;
            float S0 = 0.f, S1 = 0.f, S2 = 0.f;
            #pragma unroll
            for (int dd = 0; dd < D_; dd++) {
                float wq = sDa[dd] * sDep[d];
                S0 = fmaf(wq, fx, S0);
                S1 = fmaf(wq, fy, S1);
                S2 += wq;
                x++; fx += 1.f;
                if (x == W_) { x = 0; fx = 0.f; y++; fy += 1.f; if (y == H_) { y = 0; fy = 0.f; d++; } }
            }
            for (int n = 0; n < N_; n++) {
                float van = va[n] * invs;
                const float* kv = sKinv + n * 9;
                a0 = fmaf(van, fmaf(kv[0], S0, fmaf(kv[1], S1, kv[2] * S2)), a0);
                a1 = fmaf(van, fmaf(kv[3], S0, fmaf(kv[4], S1, kv[5] * S2)), a1);
                a2 = fmaf(van, fmaf(kv[6], S0, fmaf(kv[7], S1, kv[8] * S2)), a2);
            }
        }
        sBev[0][hy][hx] = a0;
        sBev[1][hy][hx] = a1;
        sBev[2][hy][hx] = a2;
    }
    __syncthreads();

    // phase B: conv1 3->64 from LDS, pixel-major bf16 out (global + LDS tile)
    int oy = tid >> 5, ox = tid & 31;
    int y = y0 + oy, x = x0 + ox;
    float v[27];
    #pragma unroll
    for (int ci = 0; ci < 3; ci++)
        #pragma unroll
        for (int dy = 0; dy < 3; dy++)
            #pragma unroll
            for (int dx = 0; dx < 3; dx++)
                v[ci * 9 + dy * 3 + dx] = sBev[ci][oy + dy][ox + dx];
    u16x8 pack[8];
    #pragma unroll
    for (int co = 0; co < 64; co++) {
        float acc = b1[co];
        #pragma unroll
        for (int k = 0; k < 27; k++) acc = fmaf(wl[co * 27 + k], v[k], acc);
        pack[co >> 3][co & 7] = (short)f2bf(acc);
    }
    ushort_t* dst = h1pm + (size_t)(b * HW + y * W_ + x) * 64;
    #pragma unroll
    for (int j = 0; j < 8; j++) {
        *(u16x8*)(dst + j * 8) = pack[j];
        *(u16x8*)(&sTile[tid * 64 + j * 8]) = pack[j];
    }
    __syncthreads();

    // phase C: BN1 partial stats from LDS tile
    int c8 = tid & 7;
    int lp = tid >> 3;
    float s[8] = {0,0,0,0,0,0,0,0}, q[8] = {0,0,0,0,0,0,0,0};
    for (int p = lp; p < 256; p += 32) {
        u16x8 vv = *(const u16x8*)(&sTile[p * 64 + c8 * 8]);
        #pragma unroll
        for (int e = 0; e < 8; e++) {
            float f = bf2f(vv[e]);
            s[e] += f;
            q[e] = fmaf(f, f, q[e]);
        }
    }
    #pragma unroll
    for (int e = 0; e < 8; e++) {
        s[e] += __shfl_xor(s[e], 8);  s[e] += __shfl_xor(s[e], 16); s[e] += __shfl_xor(s[e], 32);
        q[e] += __shfl_xor(q[e], 8);  q[e] += __shfl_xor(q[e], 16); q[e] += __shfl_xor(q[e], 32);
    }
    if ((tid & 56) == 0) {
        #pragma unroll
        for (int e = 0; e < 8; e++) {
            atomicAdd(&sSum[c8 * 8 + e], s[e]);
            atomicAdd(&sSq[c8 * 8 + e], q[e]);
        }
    }
    __syncthreads();
    if (tid < 64) {
        atomicAdd(ws + WS_SUM1 + tid, sSum[tid]);
        atomicAdd(ws + WS_SQ1 + tid, sSq[tid]);
    }
}

// ---- K2: conv2 MFMA implicit GEMM; BN1 fused in, bf16 h2 to scratch,
//          BN2 partial stats fused out ------------------------------------
__global__ __launch_bounds__(256) void k_conv2(const ushort_t* __restrict__ h1pm,
                                               const ushort_t* __restrict__ packedW,
                                               const float* __restrict__ b2,
                                               const float* __restrict__ g1,
                                               const float* __restrict__ bb1,
                                               float* __restrict__ ws,
                                               ushort_t* __restrict__ h2b) {
    __shared__ __align__(16) ushort_t sA[204 * 64];
    __shared__ __align__(16) ushort_t sB[3 * 4096];
    __shared__ float sSc[64], sSh[64];
    __shared__ float sRs[4][64], sRq[4][64];

    const int tid = threadIdx.x;
    if (tid < 64) {   // BN1 finalize
        const float invM = 1.f / (float)BHW;
        float m = ws[WS_SUM1 + tid] * invM;
        float var = ws[WS_SQ1 + tid] * invM - m * m;
        float sc = g1[tid] * rsqrtf(var + 1e-5f);
        sSc[tid] = sc;
        sSh[tid] = bb1[tid] - m * sc;
    }
    __syncthreads();

    const int bid = blockIdx.x;
    const int b  = bid / 352;
    const int r0 = bid - b * 352;
    const int yb = r0 / 11;
    const int xb = r0 - yb * 11;
    const int x0 = xb * 32;
    const int y0 = yb * 4;
    const ushort_t* h1p = h1pm + (size_t)b * HW * 64;

    // stage A: 204 halo pixels x 64ch, BN1+ReLU, swizzled
    for (int idx = tid; idx < 204 * 8; idx += 256) {
        int r  = idx >> 3;
        int c8 = idx & 7;
        int hy = r / 34;
        int hx = r - hy * 34;
        int py = y0 + hy - 1, px = x0 + hx - 1;
        u16x8 ov = {0, 0, 0, 0, 0, 0, 0, 0};
        if ((unsigned)py < H_ && (unsigned)px < W_) {
            u16x8 v = *(const u16x8*)(h1p + (size_t)(py * W_ + px) * 64 + c8 * 8);
            #pragma unroll
            for (int e = 0; e < 8; e++) {
                int ci = c8 * 8 + e;
                float f = fmaxf(fmaf(sSc[ci], bf2f(v[e]), sSh[ci]), 0.f);
                ov[e] = (short)f2bf(f);
            }
        }
        int slot = c8 ^ (r & 7);
        *(u16x8*)(&sA[r * 64 + slot * 8]) = ov;
    }

    const int w    = tid >> 6;
    const int lane = tid & 63;
    const int g    = lane >> 4;
    const int c16  = lane & 15;

    f32x4 acc[2][4];
    #pragma unroll
    for (int m = 0; m < 2; m++)
        #pragma unroll
        for (int n = 0; n < 4; n++)
            acc[m][n] = (f32x4){0.f, 0.f, 0.f, 0.f};

    for (int grp = 0; grp < 3; grp++) {      // grp == dy
        __syncthreads();
        const uint4* src = (const uint4*)(packedW + grp * 3 * 4096);
        uint4* dst = (uint4*)sB;
        #pragma unroll
        for (int i = 0; i < 6; i++) dst[tid + 256 * i] = src[tid + 256 * i];
        __syncthreads();
        #pragma unroll
        for (int tt = 0; tt < 3; tt++) {     // tt == dx
            bf16x8 afr[2][2];
            #pragma unroll
            for (int mrep = 0; mrep < 2; mrep++)
                #pragma unroll
                for (int kk = 0; kk < 2; kk++) {
                    int r = (w + grp) * 34 + tt + c16 + 16 * mrep;
                    int slot = (g + 4 * kk) ^ (r & 7);
                    afr[mrep][kk] = *(const bf16x8*)(&sA[r * 64 + slot * 8]);
                }
            #pragma unroll
            for (int nrep = 0; nrep < 4; nrep++) {
                int n = 16 * nrep + c16;
                #pragma unroll
                for (int kk = 0; kk < 2; kk++) {
                    int slot = (g + 4 * kk) ^ (n & 7);
                    bf16x8 bfr = *(const bf16x8*)(&sB[tt * 4096 + n * 64 + slot * 8]);
                    #pragma unroll
                    for (int mrep = 0; mrep < 2; mrep++)
                        acc[mrep][nrep] = __builtin_amdgcn_mfma_f32_16x16x32_bf16(
                            afr[mrep][kk], bfr, acc[mrep][nrep], 0, 0, 0);
                }
            }
        }
    }

    // epilogue: bias, bf16 store to scratch (channel-major), BN2 stats
    const int y = y0 + w;
    #pragma unroll
    for (int nrep = 0; nrep < 4; nrep++) {
        int co = 16 * nrep + c16;
        float bias = b2[co];
        ushort_t* dstrow = h2b + (size_t)(b * 64 + co) * HW + y * W_;
        float s = 0.f, q = 0.f;
        #pragma unroll
        for (int mrep = 0; mrep < 2; mrep++) {
            u16x4 ov;
            #pragma unroll
            for (int j = 0; j < 4; j++) {
                float val = acc[mrep][nrep][j] + bias;
                s += val;
                q = fmaf(val, val, q);
                ov[j] = f2bf(val);
            }
            *(u16x4*)(dstrow + x0 + 16 * mrep + g * 4) = ov;
        }
        s += __shfl_xor(s, 16); s += __shfl_xor(s, 32);
        q += __shfl_xor(q, 16); q += __shfl_xor(q, 32);
        if (g == 0) { sRs[w][co] = s; sRq[w][co] = q; }
    }
    __syncthreads();
    if (tid < 64) {
        float s = sRs[0][tid] + sRs[1][tid] + sRs[2][tid] + sRs[3][tid];
        float q = sRq[0][tid] + sRq[1][tid] + sRq[2][tid] + sRq[3][tid];
        atomicAdd(ws + WS_SUM2 + tid, s);
        atomicAdd(ws + WS_SQ2 + tid, q);
    }
}

// ---- K3: tail — one block per 4KB pc chunk. Chunks overlaying h2b first
//      read their own 16B of bf16 h2, emit BN2+ReLU to bev, barrier, then
//      overwrite the same 16B with pc. All other chunks: plain pc write. ---
__global__ __launch_bounds__(256) void k_tail(const float* __restrict__ depths,
                                              const float* __restrict__ ws,
                                              const float* __restrict__ g2,
                                              const float* __restrict__ bb2,
                                              float* __restrict__ out) {
    int bid = blockIdx.x, tid = threadIdx.x;
    if (bid >= CH_H2B0 && bid < CH_H2B1) {
        const ushort_t* h2b = (const ushort_t*)((const char*)out + ((size_t)CH_H2B0 * 4096));
        int f2 = (bid - CH_H2B0) * 2048 + tid * 8;      // bev element index
        int c = (f2 / HW) & 63;
        const float invM = 1.f / (float)BHW;
        float m = ws[WS_SUM2 + c] * invM;
        float var = ws[WS_SQ2 + c] * invM - m * m;
        float sc = g2[c] * rsqrtf(var + 1e-5f);
        float sh = bb2[c] - m * sc;
        u16x8 v = *(const u16x8*)(h2b + f2);            // own 16B (aliases pc chunk)
        float* bev = out + PC_SIZE;
        f32x4 a, d;
        a.x = fmaxf(fmaf(sc, bf2f(v[0]), sh), 0.f);
        a.y = fmaxf(fmaf(sc, bf2f(v[1]), sh), 0.f);
        a.z = fmaxf(fmaf(sc, bf2f(v[2]), sh), 0.f);
        a.w = fmaxf(fmaf(sc, bf2f(v[3]), sh), 0.f);
        d.x = fmaxf(fmaf(sc, bf2f(v[4]), sh), 0.f);
        d.y = fmaxf(fmaf(sc, bf2f(v[5]), sh), 0.f);
        d.z = fmaxf(fmaf(sc, bf2f(v[6]), sh), 0.f);
        d.w = fmaxf(fmaf(sc, bf2f(v[7]), sh), 0.f);
        *(f32x4*)(bev + f2) = a;
        *(f32x4*)(bev + f2 + 4) = d;
        __syncthreads();   // guarantees the h2b load drained before aliasing store
        pc_write(bid, ws, depths, out);
        return;
    }
    pc_write(bid, ws, depths, out);
}

extern "C" void kernel_launch(void* const* d_in, const int* in_sizes, int n_in,
                              void* d_out, int out_size, void* d_ws, size_t ws_size,
                              hipStream_t stream) {
    const float* K4     = (const float*)d_in[1];
    const float* vatt   = (const float*)d_in[3];
    const float* datt   = (const float*)d_in[4];
    const float* c1w    = (const float*)d_in[5];
    const float* c1b    = (const float*)d_in[6];
    const float* g1     = (const float*)d_in[7];
    const float* bb1    = (const float*)d_in[8];
    const float* c2w    = (const float*)d_in[9];
    const float* c2b    = (const float*)d_in[10];
    const float* g2     = (const float*)d_in[11];
    const float* bb2    = (const float*)d_in[12];
    const float* depths = (const float*)d_in[13];

    float* ws  = (float*)d_ws;
    char* base = (char*)d_out;
    // scratch inside pc region (overwritten only by k_tail's pc writes):
    ushort_t* h1pm    = (ushort_t*)base;                          // chunks [0,2816)
    ushort_t* packedW = (ushort_t*)(base + (12u << 20));          // chunks [3072,3091)
    ushort_t* h2b     = (ushort_t*)(base + ((size_t)CH_H2B0 * 4096)); // chunks [4096,6912)

    hipMemsetAsync(ws, 0, 640 * sizeof(float), stream);
    k_fused1<<<496, 256, 0, stream>>>(K4, datt, vatt, depths, c1w, c1b, c2w, ws, h1pm, packedW);
    k_conv2 <<<704, 256, 0, stream>>>(h1pm, packedW, c2b, g1, bb1, ws, h2b);
    k_tail  <<<NPC_BLK, 256, 0, stream>>>(depths, ws, g2, bb2, (float*)d_out);
}